// Round 1
// baseline (1125.649 us; speedup 1.0000x reference)
//
#include <hip/hip_runtime.h>
#include <hip/hip_bf16.h>
#include <cmath>

// Problem constants: B=2, S=2048, D=1024, H=16, Dh=64
#define SCALE_ 0.125f

typedef __bf16 bf16x8 __attribute__((ext_vector_type(8)));
typedef float f32x4 __attribute__((ext_vector_type(4)));

__device__ __forceinline__ unsigned short f2bf(float f) {
  unsigned int u = __builtin_bit_cast(unsigned int, f);
  u += 0x7fffu + ((u >> 16) & 1u);
  return (unsigned short)(u >> 16);
}
__device__ __forceinline__ float bf2f(unsigned short h) {
  unsigned int u = ((unsigned int)h) << 16;
  return __builtin_bit_cast(float, u);
}
__device__ __forceinline__ unsigned int pack2(float a, float b) {
  return (unsigned int)f2bf(a) | ((unsigned int)f2bf(b) << 16);
}
__device__ __forceinline__ bf16x8 bc16(uint4 u) { return __builtin_bit_cast(bf16x8, u); }
__device__ __forceinline__ f32x4 mma(bf16x8 a, bf16x8 b, f32x4 c) {
  return __builtin_amdgcn_mfma_f32_16x16x32_bf16(a, b, c, 0, 0, 0);
}

// ---------------- RoPE tables (fp64 for accuracy) ----------------
__global__ void k_tables(float* __restrict__ cosT, float* __restrict__ sinT) {
  int g = blockIdx.x * 1024 + threadIdx.x;  // 65536 = 2048*32
  int s = g >> 5, i = g & 31;
  double inv = pow(10000.0, -(double)(2 * i) / 64.0);
  double a = (double)s * inv;
  cosT[g] = (float)cos(a);
  sinT[g] = (float)sin(a);
}

// ---------------- split x -> hi/lo bf16 ----------------
__global__ void k_split_x(const float* __restrict__ x,
                          unsigned short* __restrict__ hi,
                          unsigned short* __restrict__ lo) {
  int idx = blockIdx.x * 256 + threadIdx.x;  // 1M threads, float4 each
  float4 v = ((const float4*)x)[idx];
  uint2 hv, lv;
  hv.x = pack2(v.x, v.y);
  hv.y = pack2(v.z, v.w);
  float r0 = v.x - bf2f(f2bf(v.x));
  float r1 = v.y - bf2f(f2bf(v.y));
  float r2 = v.z - bf2f(f2bf(v.z));
  float r3 = v.w - bf2f(f2bf(v.w));
  lv.x = pack2(r0, r1);
  lv.y = pack2(r2, r3);
  ((uint2*)hi)[idx] = hv;
  ((uint2*)lo)[idx] = lv;
}

// ---------------- transpose + split weights: w[K][N] -> wT[N][K] ----------------
__global__ void k_trans_w(const float* __restrict__ wq, const float* __restrict__ wk,
                          const float* __restrict__ wv, const float* __restrict__ wo,
                          unsigned short* __restrict__ qh, unsigned short* __restrict__ ql,
                          unsigned short* __restrict__ kh, unsigned short* __restrict__ kl,
                          unsigned short* __restrict__ vh, unsigned short* __restrict__ vl,
                          unsigned short* __restrict__ oh) {
  int z = blockIdx.z;
  const float* src = (z == 0) ? wq : (z == 1) ? wk : (z == 2) ? wv : wo;
  unsigned short* dsth = (z == 0) ? qh : (z == 1) ? kh : (z == 2) ? vh : oh;
  unsigned short* dstl = (z == 0) ? ql : (z == 1) ? kl : (z == 2) ? vl : nullptr;
  __shared__ float t[32][33];
  int tx = threadIdx.x, ty = threadIdx.y;
  int k0 = blockIdx.x * 32, n0 = blockIdx.y * 32;
#pragma unroll
  for (int i = 0; i < 4; ++i)
    t[ty + 8 * i][tx] = src[(k0 + ty + 8 * i) * 1024 + n0 + tx];
  __syncthreads();
#pragma unroll
  for (int i = 0; i < 4; ++i) {
    float f = t[tx][ty + 8 * i];
    int n = n0 + ty + 8 * i, k = k0 + tx;
    unsigned short hb = f2bf(f);
    dsth[n * 1024 + k] = hb;
    if (dstl) dstl[n * 1024 + k] = f2bf(f - bf2f(hb));
  }
}

// ---------------- QKV projection (split-bf16, RoPE fused) ----------------
// grid (32, 8, 3): 128x128 tiles over M=4096, N=1024; z selects wq/wk/wv
__global__ __launch_bounds__(256, 2) void k_qkv(
    const unsigned short* __restrict__ xhi, const unsigned short* __restrict__ xlo,
    const unsigned short* __restrict__ wTh0, const unsigned short* __restrict__ wTl0,
    const unsigned short* __restrict__ wTh1, const unsigned short* __restrict__ wTl1,
    const unsigned short* __restrict__ wTh2, const unsigned short* __restrict__ wTl2,
    unsigned short* __restrict__ qhi, unsigned short* __restrict__ qlo,
    unsigned short* __restrict__ khi, unsigned short* __restrict__ klo,
    unsigned short* __restrict__ vt,
    const float* __restrict__ cosT, const float* __restrict__ sinT) {
  const int z = blockIdx.z;
  const unsigned short* wh = (z == 0) ? wTh0 : (z == 1) ? wTh1 : wTh2;
  const unsigned short* wl = (z == 0) ? wTl0 : (z == 1) ? wTl1 : wTl2;
  const int m0 = blockIdx.x * 128, n0 = blockIdx.y * 128;
  const int tid = threadIdx.x, lane = tid & 63, w = tid >> 6;
  const int wm = w >> 1, wn = w & 1;
  const int lr = lane & 15, lk = (lane >> 4) * 8;

  __shared__ __align__(16) unsigned short Ah[128][40];
  __shared__ __align__(16) unsigned short Al[128][40];
  __shared__ __align__(16) unsigned short Bh[128][40];
  __shared__ __align__(16) unsigned short Bl[128][40];

  f32x4 acc[4][4];
#pragma unroll
  for (int i = 0; i < 4; ++i)
#pragma unroll
    for (int j = 0; j < 4; ++j) acc[i][j] = f32x4{0.f, 0.f, 0.f, 0.f};

  for (int kt = 0; kt < 32; ++kt) {
    const int k0 = kt * 32;
#pragma unroll
    for (int i = 0; i < 2; ++i) {
      int idx = tid + i * 256;
      int row = idx >> 2, c = (idx & 3) * 8;
      *(uint4*)&Ah[row][c] = *(const uint4*)&xhi[(m0 + row) * 1024 + k0 + c];
      *(uint4*)&Al[row][c] = *(const uint4*)&xlo[(m0 + row) * 1024 + k0 + c];
      *(uint4*)&Bh[row][c] = *(const uint4*)&wh[(n0 + row) * 1024 + k0 + c];
      *(uint4*)&Bl[row][c] = *(const uint4*)&wl[(n0 + row) * 1024 + k0 + c];
    }
    __syncthreads();
    bf16x8 ah[4], al[4], bh[4], bl[4];
#pragma unroll
    for (int f = 0; f < 4; ++f) {
      ah[f] = bc16(*(const uint4*)&Ah[wm * 64 + f * 16 + lr][lk]);
      al[f] = bc16(*(const uint4*)&Al[wm * 64 + f * 16 + lr][lk]);
      bh[f] = bc16(*(const uint4*)&Bh[wn * 64 + f * 16 + lr][lk]);
      bl[f] = bc16(*(const uint4*)&Bl[wn * 64 + f * 16 + lr][lk]);
    }
#pragma unroll
    for (int mf = 0; mf < 4; ++mf)
#pragma unroll
      for (int nf = 0; nf < 4; ++nf) {
        acc[mf][nf] = mma(ah[mf], bh[nf], acc[mf][nf]);
        acc[mf][nf] = mma(ah[mf], bl[nf], acc[mf][nf]);
        acc[mf][nf] = mma(al[mf], bh[nf], acc[mf][nf]);
      }
    __syncthreads();
  }

  // epilogue: D[row][col], row=(lane>>4)*4+r, col=lane&15 within each 16x16 frag
#pragma unroll
  for (int mf = 0; mf < 4; ++mf) {
#pragma unroll
    for (int nf = 0; nf < 4; ++nf) {
      const int col = n0 + wn * 64 + nf * 16 + lr;
      const int hh = col >> 6, dh = col & 63;
      const int mbase = m0 + wm * 64 + mf * 16 + ((lane >> 4) << 2);
      const int b = mbase >> 11;
      if (z == 2) {
        // V: store transposed (B,H,Dh,S), pack 4 consecutive s
        const int s = mbase & 2047;
        size_t vbase = ((size_t)((b * 16 + hh) * 64 + dh)) * 2048 + s;
        uint2 pk;
        pk.x = pack2(acc[mf][nf][0], acc[mf][nf][1]);
        pk.y = pack2(acc[mf][nf][2], acc[mf][nf][3]);
        *(uint2*)&vt[vbase] = pk;
      } else {
        unsigned short* dsthi = (z == 0) ? qhi : khi;
        unsigned short* dstlo = (z == 0) ? qlo : klo;
        const int fi = dh >> 1;
#pragma unroll
        for (int r = 0; r < 4; ++r) {
          const int mrow = mbase + r;
          const int s = mrow & 2047;
          float c = cosT[s * 32 + fi], sn = sinT[s * 32 + fi];
          float v = acc[mf][nf][r];
          float p = __shfl_xor(v, 1);
          float o = (dh & 1) ? (p * sn + v * c) : (v * c - p * sn);
          unsigned short hb = f2bf(o);
          size_t qi = ((size_t)((b * 16 + hh) * 2048 + s)) * 64 + dh;
          dsthi[qi] = hb;
          dstlo[qi] = f2bf(o - bf2f(hb));
        }
      }
    }
  }
}

// ---------------- fused scores + softmax + attn-write + PV ----------------
// one block per (b,h,16-row strip); 512 threads = 8 waves; dyn LDS 135424 B
__global__ __launch_bounds__(512, 2) void k_attn(
    const unsigned short* __restrict__ qhi, const unsigned short* __restrict__ qlo,
    const unsigned short* __restrict__ khi, const unsigned short* __restrict__ klo,
    const unsigned short* __restrict__ vt, const int* __restrict__ mask,
    float* __restrict__ attn, unsigned short* __restrict__ ctx) {
  extern __shared__ float sm[];          // [16][2052] scores
  float* pvpart = sm + 16 * 2052;        // [16][64] partial PV
  const int bx = blockIdx.x;
  const int b = bx >> 11, h = (bx >> 7) & 15, st = bx & 127;
  const int s0 = st * 16;
  const int tid = threadIdx.x;
  const int lane = tid & 63, w = tid >> 6;
  const int lr = lane & 15, lk = (lane >> 4) * 8;
  const int bh = b * 16 + h;
  const size_t kvbase = (size_t)bh * 2048 * 64;

  // Q fragments (A operand), K=64 in two 32-chunks
  bf16x8 qh0, qh1, ql0, ql1;
  {
    const unsigned short* qp = qhi + kvbase + (size_t)(s0 + lr) * 64 + lk;
    qh0 = bc16(*(const uint4*)qp);
    qh1 = bc16(*(const uint4*)(qp + 32));
    const unsigned short* qp2 = qlo + kvbase + (size_t)(s0 + lr) * 64 + lk;
    ql0 = bc16(*(const uint4*)qp2);
    ql1 = bc16(*(const uint4*)(qp2 + 32));
  }

  // ---- QK^T: 16 iters x (8 waves * 16 cols) = 2048 cols ----
  {
    const unsigned short* kh_p = khi + kvbase;
    const unsigned short* kl_p = klo + kvbase;
    int col = w * 16 + lr;
    uint4 a0 = *(const uint4*)&kh_p[col * 64 + lk];
    uint4 a1 = *(const uint4*)&kh_p[col * 64 + 32 + lk];
    uint4 b0 = *(const uint4*)&kl_p[col * 64 + lk];
    uint4 b1 = *(const uint4*)&kl_p[col * 64 + 32 + lk];
    int mv = mask[b * 2048 + col];
    for (int it = 0; it < 16; ++it) {
      uint4 c0 = a0, c1 = a1, e0 = b0, e1 = b1;
      int curmv = mv;
      int curcol = it * 128 + w * 16 + lr;
      if (it < 15) {
        int nc = (it + 1) * 128 + w * 16 + lr;
        a0 = *(const uint4*)&kh_p[nc * 64 + lk];
        a1 = *(const uint4*)&kh_p[nc * 64 + 32 + lk];
        b0 = *(const uint4*)&kl_p[nc * 64 + lk];
        b1 = *(const uint4*)&kl_p[nc * 64 + 32 + lk];
        mv = mask[b * 2048 + nc];
      }
      f32x4 acc0 = {0.f, 0.f, 0.f, 0.f};
      f32x4 acc1 = {0.f, 0.f, 0.f, 0.f};
      acc0 = mma(qh0, bc16(c0), acc0);
      acc0 = mma(qh1, bc16(c1), acc0);
      acc1 = mma(qh0, bc16(e0), acc1);
      acc1 = mma(qh1, bc16(e1), acc1);
      acc1 = mma(ql0, bc16(c0), acc1);
      acc1 = mma(ql1, bc16(c1), acc1);
#pragma unroll
      for (int r = 0; r < 4; ++r) {
        float sc = (acc0[r] + acc1[r]) * SCALE_;
        if (curmv == 0) sc = -1e30f;
        sm[((lane >> 4) * 4 + r) * 2052 + curcol] = sc;
      }
    }
  }
  __syncthreads();

  // ---- softmax: 8 waves * 2 rows, 32 lanes per row ----
  {
    const int row = w * 2 + (lane >> 5);
    const int sl = lane & 31;
    float* rp = sm + row * 2052;
    float mx = -3.0e38f;
#pragma unroll
    for (int i = 0; i < 16; ++i) {
      float4 v = *(const float4*)&rp[sl * 4 + i * 128];
      mx = fmaxf(mx, fmaxf(fmaxf(v.x, v.y), fmaxf(v.z, v.w)));
    }
#pragma unroll
    for (int off = 1; off <= 16; off <<= 1) mx = fmaxf(mx, __shfl_xor(mx, off));
    float sum = 0.f;
#pragma unroll
    for (int i = 0; i < 16; ++i) {
      float4 v = *(const float4*)&rp[sl * 4 + i * 128];
      sum += __expf(v.x - mx) + __expf(v.y - mx) + __expf(v.z - mx) + __expf(v.w - mx);
    }
#pragma unroll
    for (int off = 1; off <= 16; off <<= 1) sum += __shfl_xor(sum, off);
    float inv = 1.0f / sum;
    size_t abase = ((size_t)bh * 2048 + (size_t)(s0 + row)) * 2048;
#pragma unroll 4
    for (int i = 0; i < 16; ++i) {
      float4 v = *(const float4*)&rp[sl * 4 + i * 128];
      float4 e;
      e.x = __expf(v.x - mx) * inv;
      e.y = __expf(v.y - mx) * inv;
      e.z = __expf(v.z - mx) * inv;
      e.w = __expf(v.w - mx) * inv;
      *(float4*)&rp[sl * 4 + i * 128] = e;
      *(float4*)&attn[abase + sl * 4 + i * 128] = e;
    }
  }
  __syncthreads();

  // ---- PV: P[16x2048] (LDS) x V[2048x64] (vt, transposed) ----
  {
    const int d0 = (w & 3) * 16;
    const int khalf = w >> 2;
    const unsigned short* vb = vt + ((size_t)bh * 64 + d0 + lr) * 2048 + khalf * 1024;
    f32x4 o = {0.f, 0.f, 0.f, 0.f};
    uint4 vp = *(const uint4*)&vb[lk];
    for (int kt = 0; kt < 32; ++kt) {
      uint4 vc = vp;
      if (kt < 31) vp = *(const uint4*)&vb[(kt + 1) * 32 + lk];
      const float* pp = sm + lr * 2052 + khalf * 1024 + kt * 32 + lk;
      float4 f0 = *(const float4*)pp;
      float4 f1 = *(const float4*)(pp + 4);
      uint4 pu;
      pu.x = pack2(f0.x, f0.y);
      pu.y = pack2(f0.z, f0.w);
      pu.z = pack2(f1.x, f1.y);
      pu.w = pack2(f1.z, f1.w);
      o = mma(bc16(pu), bc16(vc), o);
    }
    if (khalf == 1) {
#pragma unroll
      for (int r = 0; r < 4; ++r)
        pvpart[((lane >> 4) * 4 + r) * 64 + d0 + lr] = o[r];
    }
    __syncthreads();
    if (khalf == 0) {
#pragma unroll
      for (int r = 0; r < 4; ++r) {
        int q = (lane >> 4) * 4 + r;
        float v = o[r] + pvpart[q * 64 + d0 + lr];
        ctx[((size_t)(b * 2048 + s0 + q)) * 1024 + h * 64 + d0 + lr] = f2bf(v);
      }
    }
  }
}

// ---------------- output projection: ctx[4096][1024] @ wo -> out fp32 ----------------
__global__ __launch_bounds__(256, 2) void k_outproj(
    const unsigned short* __restrict__ A, const unsigned short* __restrict__ Bt,
    float* __restrict__ out) {
  const int m0 = blockIdx.x * 128, n0 = blockIdx.y * 128;
  const int tid = threadIdx.x, lane = tid & 63, w = tid >> 6;
  const int wm = w >> 1, wn = w & 1;
  const int lr = lane & 15, lk = (lane >> 4) * 8;
  __shared__ __align__(16) unsigned short Ash[128][40];
  __shared__ __align__(16) unsigned short Bsh[128][40];
  f32x4 acc[4][4];
#pragma unroll
  for (int i = 0; i < 4; ++i)
#pragma unroll
    for (int j = 0; j < 4; ++j) acc[i][j] = f32x4{0.f, 0.f, 0.f, 0.f};

  for (int kt = 0; kt < 32; ++kt) {
    const int k0 = kt * 32;
#pragma unroll
    for (int i = 0; i < 2; ++i) {
      int idx = tid + i * 256;
      int row = idx >> 2, c = (idx & 3) * 8;
      *(uint4*)&Ash[row][c] = *(const uint4*)&A[(m0 + row) * 1024 + k0 + c];
      *(uint4*)&Bsh[row][c] = *(const uint4*)&Bt[(n0 + row) * 1024 + k0 + c];
    }
    __syncthreads();
    bf16x8 af[4], bf_[4];
#pragma unroll
    for (int f = 0; f < 4; ++f) {
      af[f] = bc16(*(const uint4*)&Ash[wm * 64 + f * 16 + lr][lk]);
      bf_[f] = bc16(*(const uint4*)&Bsh[wn * 64 + f * 16 + lr][lk]);
    }
#pragma unroll
    for (int mf = 0; mf < 4; ++mf)
#pragma unroll
      for (int nf = 0; nf < 4; ++nf)
        acc[mf][nf] = mma(af[mf], bf_[nf], acc[mf][nf]);
    __syncthreads();
  }
#pragma unroll
  for (int mf = 0; mf < 4; ++mf)
#pragma unroll
    for (int nf = 0; nf < 4; ++nf) {
      const int col = n0 + wn * 64 + nf * 16 + lr;
      const int mbase = m0 + wm * 64 + mf * 16 + ((lane >> 4) << 2);
#pragma unroll
      for (int r = 0; r < 4; ++r)
        out[(size_t)(mbase + r) * 1024 + col] = acc[mf][nf][r];
    }
}

extern "C" void kernel_launch(void* const* d_in, const int* in_sizes, int n_in,
                              void* d_out, int out_size, void* d_ws, size_t ws_size,
                              hipStream_t stream) {
  const float* x = (const float*)d_in[0];
  const int* mask = (const int*)d_in[1];
  const float* wq = (const float*)d_in[2];
  const float* wk = (const float*)d_in[3];
  const float* wv = (const float*)d_in[4];
  const float* wo = (const float*)d_in[5];
  float* out0 = (float*)d_out;
  float* attn = out0 + 4194304ull;  // 2*2048*1024

  char* ws = (char*)d_ws;
  size_t off = 0;
  auto alloc = [&](size_t bytes) -> void* {
    void* p = (void*)(ws + off);
    off += (bytes + 255) & ~(size_t)255;
    return p;
  };
  float* cosT = (float*)alloc(2048 * 32 * 4);
  float* sinT = (float*)alloc(2048 * 32 * 4);
  unsigned short* xhi = (unsigned short*)alloc(4194304ull * 2);
  unsigned short* xlo = (unsigned short*)alloc(4194304ull * 2);
  unsigned short* wqTh = (unsigned short*)alloc(1048576ull * 2);
  unsigned short* wqTl = (unsigned short*)alloc(1048576ull * 2);
  unsigned short* wkTh = (unsigned short*)alloc(1048576ull * 2);
  unsigned short* wkTl = (unsigned short*)alloc(1048576ull * 2);
  unsigned short* wvTh = (unsigned short*)alloc(1048576ull * 2);
  unsigned short* wvTl = (unsigned short*)alloc(1048576ull * 2);
  unsigned short* woT = (unsigned short*)alloc(1048576ull * 2);
  unsigned short* qhi = (unsigned short*)alloc(4194304ull * 2);
  unsigned short* qlo = (unsigned short*)alloc(4194304ull * 2);
  unsigned short* khi = (unsigned short*)alloc(4194304ull * 2);
  unsigned short* klo = (unsigned short*)alloc(4194304ull * 2);
  unsigned short* vt = (unsigned short*)alloc(4194304ull * 2);
  unsigned short* ctx = (unsigned short*)alloc(4194304ull * 2);
  (void)ws_size; (void)in_sizes; (void)n_in; (void)out_size;

  static const int ATTN_LDS = (16 * 2052 + 16 * 64) * 4;  // 135424
  hipFuncSetAttribute((const void*)k_attn,
                      hipFuncAttributeMaxDynamicSharedMemorySize, ATTN_LDS);

  k_tables<<<64, 1024, 0, stream>>>(cosT, sinT);
  k_split_x<<<4096, 256, 0, stream>>>(x, xhi, xlo);
  k_trans_w<<<dim3(32, 32, 4), dim3(32, 8), 0, stream>>>(
      wq, wk, wv, wo, wqTh, wqTl, wkTh, wkTl, wvTh, wvTl, woT);
  k_qkv<<<dim3(32, 8, 3), 256, 0, stream>>>(
      xhi, xlo, wqTh, wqTl, wkTh, wkTl, wvTh, wvTl,
      qhi, qlo, khi, klo, vt, cosT, sinT);
  k_attn<<<4096, 512, ATTN_LDS, stream>>>(qhi, qlo, khi, klo, vt, mask, attn, ctx);
  k_outproj<<<dim3(32, 8), 256, 0, stream>>>(ctx, woT, out0);
}